// Round 4
// baseline (372.075 us; speedup 1.0000x reference)
//
#include <hip/hip_runtime.h>
#include <math.h>

#define T_SEQ 1152

// ---------------------------------------------------------------------------
// Kernel 0: M[b,s,m] = sum_n spatial_w[n,s] * L_norm[b,n,m]   (B x 4 x 64)
// ---------------------------------------------------------------------------
__global__ void mKernel(const float* __restrict__ L, const float* __restrict__ sw,
                        float* __restrict__ Mbuf) {
  int b = blockIdx.x, tid = threadIdx.x;   // 256 threads
  int s = tid >> 6, m = tid & 63;
  float a = 0.f;
  #pragma unroll 4
  for (int n = 0; n < 64; ++n)
    a = fmaf(sw[n * 4 + s], L[(b * 64 + n) * 64 + m], a);
  Mbuf[b * 256 + s * 64 + m] = a;
}

// ---------------------------------------------------------------------------
// Kernel A: conv(32x1, 8->8, SAME) + LayerNorm(8) + ReLU + projection by M.
// vs R3: register-prefetch double-buffering of the X staging (T14) — part+1's
// 12 float4 global loads are issued at the start of conv(part) and land in
// VGPRs; LDS write happens after the alias barrier. HBM latency (~900cy)
// hides under the ~16K-cy conv FMA phase.
// ---------------------------------------------------------------------------
__global__ __launch_bounds__(128, 2)
void convKernel(const float* __restrict__ X, const float* __restrict__ Kw,
                const float* __restrict__ lnS, const float* __restrict__ lnB,
                const float* __restrict__ Mbuf, float* __restrict__ snn) {
  // Xs layout: [i][w][c] addr = (i*95 + w)*9 + c   (6840 floats)
  // hS layout: [c][t]    addr = c*772 + t*12 + f   (6176 floats, aliases Xs)
  __shared__ float XH[6840];
  __shared__ float Ms[256];            // [c][s]
  __shared__ float lnSs[8], lnBs[8];

  const int tile = blockIdx.x;         // 0..17
  const int b    = blockIdx.y;         // 0..63
  const int tid  = threadIdx.x;        // 0..127
  const int t0   = tile * 64;

  for (int idx = tid; idx < 256; idx += 128) {
    int s = idx >> 6, m = idx & 63;
    Ms[m * 4 + s] = Mbuf[b * 256 + idx];
  }
  if (tid < 8) { lnSs[tid] = lnS[tid]; lnBs[tid] = lnB[tid]; }

  // ---- precompute per-thread staging slots (addresses + validity)
  int offs[12];
  bool val[12];
  #pragma unroll
  for (int r = 0; r < 12; ++r) {
    int idx = r * 128 + tid;
    int w = idx >> 4, q = idx & 15;
    int tg_ = t0 - 15 + w;
    bool ok = (idx < 1520) && (tg_ >= 0) && (tg_ < T_SEQ);
    offs[r] = ok ? (tg_ * 512 + q * 4) : 0;
    val[r] = ok;
  }
  const float* xb0 = X + (size_t)(b * T_SEQ) * 512;

  const int cL = tid & 7;              // channel within part
  const int tg = tid >> 3;             // 0..15, owns t = tg*4 + ts
  float sacc[16];
  #pragma unroll
  for (int k = 0; k < 16; ++k) sacc[k] = 0.f;

  float4 pf[12];
  // prologue: prefetch part 0
  {
    const float* xp = xb0;
    #pragma unroll
    for (int r = 0; r < 12; ++r) {
      float4 v = make_float4(0.f, 0.f, 0.f, 0.f);
      if (val[r]) v = *(const float4*)(xp + offs[r]);
      pf[r] = v;
    }
  }

  #pragma unroll 1
  for (int part = 0; part < 8; ++part) {
    __syncthreads();                   // (A) prev proj reads of hS done (alias)
    // ---- write prefetched regs -> XH[(i*95+w)*9 + c]
    #pragma unroll
    for (int r = 0; r < 12; ++r) {
      int idx = r * 128 + tid;
      if (idx < 1520) {
        int w = idx >> 4, q = idx & 15;
        int c = q >> 1, i0 = (q & 1) * 4;
        XH[((i0 + 0) * 95 + w) * 9 + c] = pf[r].x;
        XH[((i0 + 1) * 95 + w) * 9 + c] = pf[r].y;
        XH[((i0 + 2) * 95 + w) * 9 + c] = pf[r].z;
        XH[((i0 + 3) * 95 + w) * 9 + c] = pf[r].w;
      }
    }
    __syncthreads();                   // (B) XH ready

    // ---- issue prefetch for part+1 (lands during conv)
    if (part < 7) {
      const float* xp = xb0 + (part + 1) * 64;
      #pragma unroll
      for (int r = 0; r < 12; ++r) {
        float4 v = make_float4(0.f, 0.f, 0.f, 0.f);
        if (val[r]) v = *(const float4*)(xp + offs[r]);
        pf[r] = v;
      }
    }

    // ---- conv: acc[ts][f], output t = t0 + tg*4 + ts
    float acc[4][8];
    #pragma unroll
    for (int ts = 0; ts < 4; ++ts)
      #pragma unroll
      for (int f = 0; f < 8; ++f) acc[ts][f] = 0.f;

    #pragma unroll 1
    for (int i = 0; i < 8; ++i) {
      const float* xrow = &XH[(i * 95 + tg * 4) * 9 + cL];
      #pragma unroll 1
      for (int g = 0; g < 4; ++g) {
        float xw[11];
        #pragma unroll
        for (int u = 0; u < 11; ++u) xw[u] = xrow[(g * 8 + u) * 9];
        #pragma unroll
        for (int u = 0; u < 8; ++u) {
          const float* kp = Kw + (g * 8 + u) * 64 + i * 8;  // wave-uniform -> s_load
          const float4 k0 = *(const float4*)kp;
          const float4 k1 = *(const float4*)(kp + 4);
          #pragma unroll
          for (int ts = 0; ts < 4; ++ts) {
            float xv = xw[u + ts];
            acc[ts][0] = fmaf(xv, k0.x, acc[ts][0]);
            acc[ts][1] = fmaf(xv, k0.y, acc[ts][1]);
            acc[ts][2] = fmaf(xv, k0.z, acc[ts][2]);
            acc[ts][3] = fmaf(xv, k0.w, acc[ts][3]);
            acc[ts][4] = fmaf(xv, k1.x, acc[ts][4]);
            acc[ts][5] = fmaf(xv, k1.y, acc[ts][5]);
            acc[ts][6] = fmaf(xv, k1.z, acc[ts][6]);
            acc[ts][7] = fmaf(xv, k1.w, acc[ts][7]);
          }
        }
      }
    }
    __syncthreads();                   // (C) XH reads done before h overwrite

    // ---- LayerNorm(8) + ReLU -> hS[c][t] (b128 writes)
    #pragma unroll
    for (int ts = 0; ts < 4; ++ts) {
      float mu = 0.f;
      #pragma unroll
      for (int f = 0; f < 8; ++f) mu += acc[ts][f];
      mu *= 0.125f;
      float var = 0.f;
      #pragma unroll
      for (int f = 0; f < 8; ++f) { float d = acc[ts][f] - mu; var += d * d; }
      var *= 0.125f;
      float r = 1.0f / sqrtf(var + 1e-6f);
      float hv[8];
      #pragma unroll
      for (int f = 0; f < 8; ++f) {
        float h = (acc[ts][f] - mu) * r * lnSs[f] + lnBs[f];
        hv[f] = fmaxf(h, 0.f);
      }
      int t = tg * 4 + ts;
      *(float4*)&XH[cL * 772 + t * 12]     = make_float4(hv[0], hv[1], hv[2], hv[3]);
      *(float4*)&XH[cL * 772 + t * 12 + 4] = make_float4(hv[4], hv[5], hv[6], hv[7]);
    }
    __syncthreads();                   // (D) hS ready

    // ---- projection partial: snn[t, s*8+f] += sum_c M[c,s] * h[c,t,f]
    #pragma unroll
    for (int k = 0; k < 16; ++k) {
      int idx = k * 128 + tid;         // 0..2047 = t*32 + (s*8+f)
      int t = idx >> 5, rr = idx & 31, s = rr >> 3, f = rr & 7;
      float v = 0.f;
      #pragma unroll
      for (int c2 = 0; c2 < 8; ++c2)
        v = fmaf(XH[c2 * 772 + t * 12 + f], Ms[(part * 8 + c2) * 4 + s], v);
      sacc[k] += v;
    }
  }

  // ---- write snn tile
  #pragma unroll
  for (int k = 0; k < 16; ++k) {
    int idx = k * 128 + tid;
    int t = idx >> 5, rr = idx & 31;
    snn[((size_t)(b * T_SEQ) + t0 + t) * 32 + rr] = sacc[k];
  }
}

// ---------------------------------------------------------------------------
// Kernel B: LIF scan. 16 blocks x 64 threads; each thread runs TWO (b,j)
// chains interleaved for ILP on the dependent-FMA chain.
// ---------------------------------------------------------------------------
__global__ void scanKernel(const float* __restrict__ snn, float* __restrict__ flat,
                           float* __restrict__ spkPart) {
  const int tid = threadIdx.x;        // 0..63
  const int j = tid & 31;
  const int g = tid >> 5;             // 0..1
  const int pr = blockIdx.x * 2 + g;  // pair 0..31
  const int b0 = pr * 2, b1 = b0 + 1;
  const float* base0 = snn + (size_t)b0 * T_SEQ * 32 + j;
  const float* base1 = snn + (size_t)b1 * T_SEQ * 32 + j;

  float m10 = 0.f, m20 = 0.f, mo0 = 0.f, s10 = 0.f, s20 = 0.f;
  float m11 = 0.f, m21 = 0.f, mo1 = 0.f, s11 = 0.f, s21 = 0.f;

  for (int ch = 0; ch < 48; ++ch) {
    float parts0[2], parts1[2];
    #pragma unroll
    for (int half = 0; half < 2; ++half) {
      float x0[12], x1[12];
      #pragma unroll
      for (int u = 0; u < 12; ++u) {
        int t = ch * 24 + half * 12 + u;
        x0[u] = base0[(size_t)t * 32];
        x1[u] = base1[(size_t)t * 32];
      }
      float acc0 = 0.f, acc1 = 0.f;
      #pragma unroll
      for (int u = 0; u < 12; ++u) {
        m10 = m10 * 0.8f + x0[u];
        float sp1a = (m10 > 0.5f) ? 1.f : 0.f;  m10 -= sp1a * 0.5f;
        m20 = m20 * 0.9f + sp1a;
        float sp2a = (m20 > 0.5f) ? 1.f : 0.f;  m20 -= sp2a * 0.5f;
        mo0 = mo0 * 0.95f + sp2a;
        s10 += sp1a; s20 += sp2a; acc0 += mo0;

        m11 = m11 * 0.8f + x1[u];
        float sp1b = (m11 > 0.5f) ? 1.f : 0.f;  m11 -= sp1b * 0.5f;
        m21 = m21 * 0.9f + sp1b;
        float sp2b = (m21 > 0.5f) ? 1.f : 0.f;  m21 -= sp2b * 0.5f;
        mo1 = mo1 * 0.95f + sp2b;
        s11 += sp1b; s21 += sp2b; acc1 += mo1;
      }
      parts0[half] = acc0; parts1[half] = acc1;
    }
    flat[b0 * 3072 + ch * 64 + j]      = parts0[0] / 12.0f;
    flat[b0 * 3072 + ch * 64 + 32 + j] = parts0[1] / 12.0f;
    flat[b1 * 3072 + ch * 64 + j]      = parts1[0] / 12.0f;
    flat[b1 * 3072 + ch * 64 + 32 + j] = parts1[1] / 12.0f;
  }
  for (int off = 16; off > 0; off >>= 1) {
    s10 += __shfl_down(s10, off, 32);
    s20 += __shfl_down(s20, off, 32);
    s11 += __shfl_down(s11, off, 32);
    s21 += __shfl_down(s21, off, 32);
  }
  if (j == 0) {
    spkPart[b0 * 2] = s10; spkPart[b0 * 2 + 1] = s20;
    spkPart[b1 * 2] = s11; spkPart[b1 * 2 + 1] = s21;
  }
}

// ---------------------------------------------------------------------------
// Kernel C: y = gelu(flat @ W1 + b1); logits = y @ W2 + b2 ; firing rate.
// ---------------------------------------------------------------------------
__global__ void mlpKernel(const float* __restrict__ flat, const float* __restrict__ W1,
                          const float* __restrict__ b1, const float* __restrict__ W2,
                          const float* __restrict__ b2, const float* __restrict__ spkPart,
                          float* __restrict__ out) {
  if (blockIdx.x == 64) {
    if (threadIdx.x == 0) {
      float s1 = 0.f, s2 = 0.f;
      for (int i = 0; i < 64; ++i) { s1 += spkPart[2 * i]; s2 += spkPart[2 * i + 1]; }
      out[256] = (s1 + s2) * 0.5f / (64.0f * 1152.0f * 32.0f);
    }
    return;
  }
  const int b = blockIdx.x;
  const int tid = threadIdx.x;        // 256
  const int u = tid & 31, kc = tid >> 5;
  __shared__ float red[256];
  __shared__ float ys[32];
  float p = 0.f;
  const int kbeg = kc * 384, kend = kbeg + 384;
  #pragma unroll 4
  for (int k = kbeg; k < kend; ++k)
    p = fmaf(flat[b * 3072 + k], W1[k * 32 + u], p);
  red[tid] = p;
  __syncthreads();
  if (kc == 0) {
    float y = b1[u];
    #pragma unroll
    for (int q = 0; q < 8; ++q) y += red[q * 32 + u];
    float y3 = y * y * y;
    float th = tanhf(0.7978845608028654f * (y + 0.044715f * y3));
    ys[u] = 0.5f * y * (1.0f + th);
  }
  __syncthreads();
  if (tid < 4) {
    float accv = b2[tid];
    #pragma unroll
    for (int q = 0; q < 32; ++q) accv = fmaf(ys[q], W2[q * 4 + tid], accv);
    out[b * 4 + tid] = accv;
  }
}

// ---------------------------------------------------------------------------
extern "C" void kernel_launch(void* const* d_in, const int* in_sizes, int n_in,
                              void* d_out, int out_size, void* d_ws, size_t ws_size,
                              hipStream_t stream) {
  const float* L   = (const float*)d_in[0];
  const float* X   = (const float*)d_in[1];
  // d_in[2] = deterministic (unused)
  const float* Kw  = (const float*)d_in[3];
  const float* lnS = (const float*)d_in[4];
  const float* lnB = (const float*)d_in[5];
  const float* sw  = (const float*)d_in[6];
  const float* W1  = (const float*)d_in[7];
  const float* b1  = (const float*)d_in[8];
  const float* W2  = (const float*)d_in[9];
  const float* b2  = (const float*)d_in[10];

  float* ws   = (float*)d_ws;
  float* Mbuf = ws;                       // 64*4*64      = 16384
  float* snn  = Mbuf + 16384;             // 64*1152*32   = 2359296
  float* flat = snn + 2359296;            // 64*3072      = 196608
  float* spk  = flat + 196608;            // 128
  float* out  = (float*)d_out;

  mKernel<<<64, 256, 0, stream>>>(L, sw, Mbuf);
  convKernel<<<dim3(18, 64), 128, 0, stream>>>(X, Kw, lnS, lnB, Mbuf, snn);
  scanKernel<<<16, 64, 0, stream>>>(snn, flat, spk);
  mlpKernel<<<65, 256, 0, stream>>>(flat, W1, b1, W2, b2, spk, out);
}

// Round 5
// 341.616 us; speedup vs baseline: 1.0892x; 1.0892x over previous
//
#include <hip/hip_runtime.h>
#include <math.h>

#define T_SEQ 1152

// ---------------------------------------------------------------------------
// Kernel 0: M[b,s,m] = sum_n spatial_w[n,s] * L_norm[b,n,m]   (B x 4 x 64)
// ---------------------------------------------------------------------------
__global__ void mKernel(const float* __restrict__ L, const float* __restrict__ sw,
                        float* __restrict__ Mbuf) {
  int b = blockIdx.x, tid = threadIdx.x;   // 256 threads
  int s = tid >> 6, m = tid & 63;
  float a = 0.f;
  #pragma unroll 4
  for (int n = 0; n < 64; ++n)
    a = fmaf(sw[n * 4 + s], L[(b * 64 + n) * 64 + m], a);
  Mbuf[b * 256 + s * 64 + m] = a;
}

// ---------------------------------------------------------------------------
// Kernel A (restructured): conv(32x1, 8->8, SAME) + LayerNorm(8) + ReLU +
// projection by M, writing snn[b,t,32].
//
// vs R4: NO LDS staging of X — each thread reads its own 35-t float4 window
// directly from global (L1/L2 serve the 9x intra-block overlap). Block =
// 256 thr = 4 t-groups x 64 c, t-tile = 16 -> grid 4608 blocks (4x more
// waves). One barrier per block (h-tile in LDS for the c-reduction).
// XCD-chunked tile swizzle keeps halo re-reads inside one XCD's L2.
// ---------------------------------------------------------------------------
__global__ __launch_bounds__(256, 4)
void convKernel(const float* __restrict__ X, const float* __restrict__ Kw,
                const float* __restrict__ lnS, const float* __restrict__ lnB,
                const float* __restrict__ Mbuf, float* __restrict__ snn) {
  __shared__ float hS[16 * 520];      // [t][c*8+f], row stride 520 (pad)
  __shared__ float Ms[256];           // [c][s]

  // XCD-chunked swizzle: XCD k (= bid%8) owns tiles [9k, 9k+9) across all b.
  const int bid = blockIdx.x;         // 0..4607
  const int k8  = bid & 7;
  const int j   = bid >> 3;           // 0..575
  const int b   = j / 9;
  const int tile = k8 * 9 + (j - b * 9);   // 0..71

  const int tid = threadIdx.x;        // 0..255
  const int c   = tid & 63;
  const int tg  = tid >> 6;           // 0..3
  const int t0  = tile * 16;
  const int tb  = t0 + tg * 4;        // thread's first output t

  Ms[(tid & 63) * 4 + (tid >> 6)] = Mbuf[b * 256 + tid];   // [c][s] transpose

  float acc[4][8];
  #pragma unroll
  for (int ts = 0; ts < 4; ++ts)
    #pragma unroll
    for (int f = 0; f < 8; ++f) acc[ts][f] = 0.f;

  const float4* X4 = (const float4*)X;
  const size_t rowBase = (size_t)b * T_SEQ * 64;   // float4-pair rows
  const bool interior = (tile >= 1 && tile <= 70);

  #pragma unroll 1
  for (int ih = 0; ih < 2; ++ih) {     // input-channel half (i = ih*4+q)
    #pragma unroll 1
    for (int g = 0; g < 4; ++g) {      // kh-groups of 8
      const int tw0 = tb + g * 8 - 15;
      float4 xw[11];
      if (interior) {
        #pragma unroll
        for (int w = 0; w < 11; ++w)
          xw[w] = X4[(((rowBase + (size_t)(tw0 + w) * 64 + c) << 1) + ih)];
      } else {
        #pragma unroll
        for (int w = 0; w < 11; ++w) {
          int t = tw0 + w;
          float4 v = make_float4(0.f, 0.f, 0.f, 0.f);
          if ((unsigned)t < (unsigned)T_SEQ)
            v = X4[(((rowBase + (size_t)t * 64 + c) << 1) + ih)];
          xw[w] = v;
        }
      }
      #pragma unroll
      for (int u = 0; u < 8; ++u) {
        const float* kp = Kw + (g * 8 + u) * 64 + ih * 32;  // uniform -> s_load
        #pragma unroll
        for (int q = 0; q < 4; ++q) {
          const float* kq = kp + q * 8;
          #pragma unroll
          for (int ts = 0; ts < 4; ++ts) {
            float xv = ((const float*)&xw[u + ts])[q];
            #pragma unroll
            for (int f = 0; f < 8; ++f)
              acc[ts][f] = fmaf(xv, kq[f], acc[ts][f]);
          }
        }
      }
    }
  }

  // ---- LayerNorm(8) + ReLU -> hS[t][c*8+f]
  #pragma unroll
  for (int ts = 0; ts < 4; ++ts) {
    float mu = 0.f;
    #pragma unroll
    for (int f = 0; f < 8; ++f) mu += acc[ts][f];
    mu *= 0.125f;
    float var = 0.f;
    #pragma unroll
    for (int f = 0; f < 8; ++f) { float d = acc[ts][f] - mu; var += d * d; }
    var *= 0.125f;
    float r = 1.0f / sqrtf(var + 1e-6f);
    float hv[8];
    #pragma unroll
    for (int f = 0; f < 8; ++f) {
      float h = (acc[ts][f] - mu) * r * lnS[f] + lnB[f];   // lnS/lnB uniform -> s_load
      hv[f] = fmaxf(h, 0.f);
    }
    int tl = tg * 4 + ts;
    *(float4*)&hS[tl * 520 + c * 8]     = make_float4(hv[0], hv[1], hv[2], hv[3]);
    *(float4*)&hS[tl * 520 + c * 8 + 4] = make_float4(hv[4], hv[5], hv[6], hv[7]);
  }
  __syncthreads();

  // ---- projection: snn[t, s*8+f] = sum_c Ms[c][s] * h[t][c][f]
  {
    const int rr = tid & 31, s = rr >> 3, f = rr & 7;
    const int tA = tid >> 5;            // 0..7 ; thread also does tA+8
    float v0 = 0.f, v1 = 0.f;
    #pragma unroll 16
    for (int c2 = 0; c2 < 64; ++c2) {
      float m = Ms[c2 * 4 + s];
      v0 = fmaf(hS[tA * 520 + c2 * 8 + f], m, v0);
      v1 = fmaf(hS[(tA + 8) * 520 + c2 * 8 + f], m, v1);
    }
    snn[((size_t)b * T_SEQ + t0 + tA) * 32 + rr]     = v0;
    snn[((size_t)b * T_SEQ + t0 + tA + 8) * 32 + rr] = v1;
  }
}

// ---------------------------------------------------------------------------
// Kernel B: LIF scan. 16 blocks x 64 threads; each thread runs TWO (b,j)
// chains interleaved for ILP on the dependent-FMA chain.
// ---------------------------------------------------------------------------
__global__ void scanKernel(const float* __restrict__ snn, float* __restrict__ flat,
                           float* __restrict__ spkPart) {
  const int tid = threadIdx.x;        // 0..63
  const int j = tid & 31;
  const int g = tid >> 5;             // 0..1
  const int pr = blockIdx.x * 2 + g;  // pair 0..31
  const int b0 = pr * 2, b1 = b0 + 1;
  const float* base0 = snn + (size_t)b0 * T_SEQ * 32 + j;
  const float* base1 = snn + (size_t)b1 * T_SEQ * 32 + j;

  float m10 = 0.f, m20 = 0.f, mo0 = 0.f, s10 = 0.f, s20 = 0.f;
  float m11 = 0.f, m21 = 0.f, mo1 = 0.f, s11 = 0.f, s21 = 0.f;

  for (int ch = 0; ch < 48; ++ch) {
    float parts0[2], parts1[2];
    #pragma unroll
    for (int half = 0; half < 2; ++half) {
      float x0[12], x1[12];
      #pragma unroll
      for (int u = 0; u < 12; ++u) {
        int t = ch * 24 + half * 12 + u;
        x0[u] = base0[(size_t)t * 32];
        x1[u] = base1[(size_t)t * 32];
      }
      float acc0 = 0.f, acc1 = 0.f;
      #pragma unroll
      for (int u = 0; u < 12; ++u) {
        m10 = m10 * 0.8f + x0[u];
        float sp1a = (m10 > 0.5f) ? 1.f : 0.f;  m10 -= sp1a * 0.5f;
        m20 = m20 * 0.9f + sp1a;
        float sp2a = (m20 > 0.5f) ? 1.f : 0.f;  m20 -= sp2a * 0.5f;
        mo0 = mo0 * 0.95f + sp2a;
        s10 += sp1a; s20 += sp2a; acc0 += mo0;

        m11 = m11 * 0.8f + x1[u];
        float sp1b = (m11 > 0.5f) ? 1.f : 0.f;  m11 -= sp1b * 0.5f;
        m21 = m21 * 0.9f + sp1b;
        float sp2b = (m21 > 0.5f) ? 1.f : 0.f;  m21 -= sp2b * 0.5f;
        mo1 = mo1 * 0.95f + sp2b;
        s11 += sp1b; s21 += sp2b; acc1 += mo1;
      }
      parts0[half] = acc0; parts1[half] = acc1;
    }
    flat[b0 * 3072 + ch * 64 + j]      = parts0[0] / 12.0f;
    flat[b0 * 3072 + ch * 64 + 32 + j] = parts0[1] / 12.0f;
    flat[b1 * 3072 + ch * 64 + j]      = parts1[0] / 12.0f;
    flat[b1 * 3072 + ch * 64 + 32 + j] = parts1[1] / 12.0f;
  }
  for (int off = 16; off > 0; off >>= 1) {
    s10 += __shfl_down(s10, off, 32);
    s20 += __shfl_down(s20, off, 32);
    s11 += __shfl_down(s11, off, 32);
    s21 += __shfl_down(s21, off, 32);
  }
  if (j == 0) {
    spkPart[b0 * 2] = s10; spkPart[b0 * 2 + 1] = s20;
    spkPart[b1 * 2] = s11; spkPart[b1 * 2 + 1] = s21;
  }
}

// ---------------------------------------------------------------------------
// Kernel C: y = gelu(flat @ W1 + b1); logits = y @ W2 + b2 ; firing rate.
// ---------------------------------------------------------------------------
__global__ void mlpKernel(const float* __restrict__ flat, const float* __restrict__ W1,
                          const float* __restrict__ b1, const float* __restrict__ W2,
                          const float* __restrict__ b2, const float* __restrict__ spkPart,
                          float* __restrict__ out) {
  if (blockIdx.x == 64) {
    if (threadIdx.x == 0) {
      float s1 = 0.f, s2 = 0.f;
      for (int i = 0; i < 64; ++i) { s1 += spkPart[2 * i]; s2 += spkPart[2 * i + 1]; }
      out[256] = (s1 + s2) * 0.5f / (64.0f * 1152.0f * 32.0f);
    }
    return;
  }
  const int b = blockIdx.x;
  const int tid = threadIdx.x;        // 256
  const int u = tid & 31, kc = tid >> 5;
  __shared__ float red[256];
  __shared__ float ys[32];
  float p = 0.f;
  const int kbeg = kc * 384, kend = kbeg + 384;
  #pragma unroll 4
  for (int k = kbeg; k < kend; ++k)
    p = fmaf(flat[b * 3072 + k], W1[k * 32 + u], p);
  red[tid] = p;
  __syncthreads();
  if (kc == 0) {
    float y = b1[u];
    #pragma unroll
    for (int q = 0; q < 8; ++q) y += red[q * 32 + u];
    float y3 = y * y * y;
    float th = tanhf(0.7978845608028654f * (y + 0.044715f * y3));
    ys[u] = 0.5f * y * (1.0f + th);
  }
  __syncthreads();
  if (tid < 4) {
    float accv = b2[tid];
    #pragma unroll
    for (int q = 0; q < 32; ++q) accv = fmaf(ys[q], W2[q * 4 + tid], accv);
    out[b * 4 + tid] = accv;
  }
}

// ---------------------------------------------------------------------------
extern "C" void kernel_launch(void* const* d_in, const int* in_sizes, int n_in,
                              void* d_out, int out_size, void* d_ws, size_t ws_size,
                              hipStream_t stream) {
  const float* L   = (const float*)d_in[0];
  const float* X   = (const float*)d_in[1];
  // d_in[2] = deterministic (unused)
  const float* Kw  = (const float*)d_in[3];
  const float* lnS = (const float*)d_in[4];
  const float* lnB = (const float*)d_in[5];
  const float* sw  = (const float*)d_in[6];
  const float* W1  = (const float*)d_in[7];
  const float* b1  = (const float*)d_in[8];
  const float* W2  = (const float*)d_in[9];
  const float* b2  = (const float*)d_in[10];

  float* ws   = (float*)d_ws;
  float* Mbuf = ws;                       // 64*4*64      = 16384
  float* snn  = Mbuf + 16384;             // 64*1152*32   = 2359296
  float* flat = snn + 2359296;            // 64*3072      = 196608
  float* spk  = flat + 196608;            // 128
  float* out  = (float*)d_out;

  mKernel<<<64, 256, 0, stream>>>(L, sw, Mbuf);
  convKernel<<<4608, 256, 0, stream>>>(X, Kw, lnS, lnB, Mbuf, snn);
  scanKernel<<<16, 64, 0, stream>>>(snn, flat, spk);
  mlpKernel<<<65, 256, 0, stream>>>(flat, W1, b1, W2, b2, spk, out);
}

// Round 6
// 294.832 us; speedup vs baseline: 1.2620x; 1.1587x over previous
//
#include <hip/hip_runtime.h>
#include <math.h>

#define T_SEQ 1152

typedef __attribute__((ext_vector_type(8))) short bf16x8;
typedef __attribute__((ext_vector_type(4))) float f32x4;

__device__ __forceinline__ unsigned short f2bf(float x) {
  unsigned u = __builtin_bit_cast(unsigned, x);
  return (unsigned short)((u + 0x7fffu + ((u >> 16) & 1u)) >> 16);
}
__device__ __forceinline__ float bf2f(unsigned short h) {
  return __builtin_bit_cast(float, (unsigned)h << 16);
}
// butterfly-add over 8-lane groups via DPP: masks xor1(quad_perm 1,0,3,2),
// xor2(quad_perm 2,3,0,1), xor7(row_half_mirror). No LDS traffic.
template <int CTRL>
__device__ __forceinline__ float xadd(float v) {
  int i = __builtin_bit_cast(int, v);
  int p = __builtin_amdgcn_update_dpp(i, i, CTRL, 0xf, 0xf, false);
  return v + __builtin_bit_cast(float, p);
}
__device__ __forceinline__ float sum8(float v) {
  return xadd<0x141>(xadd<0x4E>(xadd<0xB1>(v)));
}

// ---------------------------------------------------------------------------
// Kernel 0: M[b,m,s] = sum_n spatial_w[n,s] * L_norm[b,n,m]  (transposed out)
// ---------------------------------------------------------------------------
__global__ void mKernel(const float* __restrict__ L, const float* __restrict__ sw,
                        float* __restrict__ Mbuf) {
  int b = blockIdx.x, tid = threadIdx.x;   // 256 threads
  int s = tid >> 6, m = tid & 63;
  float a = 0.f;
  #pragma unroll 4
  for (int n = 0; n < 64; ++n)
    a = fmaf(sw[n * 4 + s], L[(b * 64 + n) * 64 + m], a);
  Mbuf[b * 256 + m * 4 + s] = a;           // [b][m][s]
}

// ---------------------------------------------------------------------------
// Kernel A (MFMA): conv(32x1, 8->8, SAME) + LayerNorm(8) + ReLU + projection.
// GEMM view: out[(t,c), f] = sum_{kh,i} X[t+kh-15, c, i] * K[kh, i, f].
// mfma_f32_16x16x32_bf16, 3-term split-bf16 (hh + hl + lh).
// Block: 256 thr = 4 waves; t-tile 64 (16 t per wave); c-parts of 8.
// LDS: X hi/lo as 16B rows [c][t][i], XOR-swizzled. B-frags (K) in VGPRs.
// LN cross-lane via DPP; projection in registers with s_loaded M.
// ---------------------------------------------------------------------------
__global__ __launch_bounds__(256, 4)
void convKernel(const float* __restrict__ X, const float* __restrict__ Kw,
                const float* __restrict__ lnS, const float* __restrict__ lnB,
                const float* __restrict__ Mbuf, float* __restrict__ snn) {
  __shared__ int4 XhS[8 * 96];   // [c2][swz(tl)] : 8 bf16 (i=0..7) per row
  __shared__ int4 XlS[8 * 96];

  const int bid  = blockIdx.x;         // 0..1151
  const int b    = bid / 18;
  const int tile = bid - b * 18;       // 0..17
  const int t0   = tile * 64;
  const int tid  = threadIdx.x;        // 0..255
  const int lane = tid & 63;
  const int wid  = tid >> 6;           // wave 0..3
  const int w16  = wid * 16;           // wave's t offset in tile
  const int f    = lane & 15;          // MFMA col (f<8 real)
  const int rg   = lane >> 4;          // row group (rows rg*4 .. rg*4+3)
  const int laneoff = (lane & 15) + rg;

  // ---- B-frags: K[kh][i][f] -> bf16 hi/lo, lane holds col f, kh=4q+rg, j=i
  bf16x8 bhi[8], blo[8];
  #pragma unroll
  for (int q = 0; q < 8; ++q) {
    #pragma unroll
    for (int j = 0; j < 8; ++j) {
      float kv = (f < 8) ? Kw[(4 * q + rg) * 64 + j * 8 + f] : 0.f;
      unsigned short h = f2bf(kv);
      unsigned short l = f2bf(kv - bf2f(h));
      bhi[q][j] = (short)h;
      blo[q][j] = (short)l;
    }
  }
  const float lnSv = lnS[f & 7];
  const float lnBv = lnB[f & 7];

  float pacc[4][4];
  #pragma unroll
  for (int r = 0; r < 4; ++r)
    #pragma unroll
    for (int s = 0; s < 4; ++s) pacc[r][s] = 0.f;

  const float* xb = X + (size_t)(b * T_SEQ) * 512;

  #pragma unroll 1
  for (int part = 0; part < 8; ++part) {
    if (part) __syncthreads();         // prev compute reads done
    // ---- stage: rows (c2, tl) -> bf16 hi/lo, swizzled 16B rows
    #pragma unroll 1
    for (int r = tid; r < 760; r += 256) {
      int c2 = r / 95;
      int tl = r - c2 * 95;
      int t  = t0 - 15 + tl;
      float x[8];
      if ((unsigned)t < (unsigned)T_SEQ) {
        const float4 a0 = *(const float4*)&xb[(size_t)t * 512 + (part * 8 + c2) * 8];
        const float4 a1 = *(const float4*)&xb[(size_t)t * 512 + (part * 8 + c2) * 8 + 4];
        x[0]=a0.x; x[1]=a0.y; x[2]=a0.z; x[3]=a0.w;
        x[4]=a1.x; x[5]=a1.y; x[6]=a1.z; x[7]=a1.w;
      } else {
        #pragma unroll
        for (int j = 0; j < 8; ++j) x[j] = 0.f;
      }
      unsigned hh[8], ll[8];
      #pragma unroll
      for (int j = 0; j < 8; ++j) {
        hh[j] = f2bf(x[j]);
        ll[j] = f2bf(x[j] - bf2f((unsigned short)hh[j]));
      }
      int4 vh, vl;
      vh.x = (int)(hh[0] | (hh[1] << 16)); vh.y = (int)(hh[2] | (hh[3] << 16));
      vh.z = (int)(hh[4] | (hh[5] << 16)); vh.w = (int)(hh[6] | (hh[7] << 16));
      vl.x = (int)(ll[0] | (ll[1] << 16)); vl.y = (int)(ll[2] | (ll[3] << 16));
      vl.z = (int)(ll[4] | (ll[5] << 16)); vl.w = (int)(ll[6] | (ll[7] << 16));
      int row = tl ^ ((tl >> 3) & 3);    // bank swizzle (involution)
      XhS[c2 * 96 + row] = vh;
      XlS[c2 * 96 + row] = vl;
    }
    __syncthreads();

    // ---- per channel: 8 k-slices x 3 split MFMAs -> LN -> proj
    #pragma unroll 1
    for (int c2 = 0; c2 < 8; ++c2) {
      f32x4 acc = {0.f, 0.f, 0.f, 0.f};
      #pragma unroll
      for (int q = 0; q < 8; ++q) {
        int tl = w16 + laneoff + 4 * q;
        int row = tl ^ ((tl >> 3) & 3);
        bf16x8 ah = __builtin_bit_cast(bf16x8, XhS[c2 * 96 + row]);
        bf16x8 al = __builtin_bit_cast(bf16x8, XlS[c2 * 96 + row]);
        acc = __builtin_amdgcn_mfma_f32_16x16x32_bf16(ah, bhi[q], acc, 0, 0, 0);
        acc = __builtin_amdgcn_mfma_f32_16x16x32_bf16(ah, blo[q], acc, 0, 0, 0);
        acc = __builtin_amdgcn_mfma_f32_16x16x32_bf16(al, bhi[q], acc, 0, 0, 0);
      }
      // LayerNorm over f (8 lanes) via DPP butterfly, then ReLU
      float hres[4];
      #pragma unroll
      for (int r = 0; r < 4; ++r) {
        float mu = sum8(acc[r]) * 0.125f;
        float d  = acc[r] - mu;
        float va = sum8(d * d) * 0.125f;
        float rs = 1.0f / sqrtf(va + 1e-6f);
        hres[r] = fmaxf(d * rs * lnSv + lnBv, 0.f);
      }
      const float4 Mc = *(const float4*)(Mbuf + b * 256 + (part * 8 + c2) * 4);
      #pragma unroll
      for (int r = 0; r < 4; ++r) {
        pacc[r][0] = fmaf(hres[r], Mc.x, pacc[r][0]);
        pacc[r][1] = fmaf(hres[r], Mc.y, pacc[r][1]);
        pacc[r][2] = fmaf(hres[r], Mc.z, pacc[r][2]);
        pacc[r][3] = fmaf(hres[r], Mc.w, pacc[r][3]);
      }
    }
  }

  // ---- store snn[b, t, s*8+f]
  if (f < 8) {
    const size_t base = (size_t)b * T_SEQ + t0 + w16 + rg * 4;
    #pragma unroll
    for (int r = 0; r < 4; ++r)
      #pragma unroll
      for (int s = 0; s < 4; ++s)
        snn[(base + r) * 32 + s * 8 + f] = pacc[r][s];
  }
}

// ---------------------------------------------------------------------------
// Kernel B: LIF scan. 16 blocks x 64 threads; each thread runs TWO (b,j)
// chains interleaved for ILP on the dependent-FMA chain.
// ---------------------------------------------------------------------------
__global__ void scanKernel(const float* __restrict__ snn, float* __restrict__ flat,
                           float* __restrict__ spkPart) {
  const int tid = threadIdx.x;        // 0..63
  const int j = tid & 31;
  const int g = tid >> 5;             // 0..1
  const int pr = blockIdx.x * 2 + g;  // pair 0..31
  const int b0 = pr * 2, b1 = b0 + 1;
  const float* base0 = snn + (size_t)b0 * T_SEQ * 32 + j;
  const float* base1 = snn + (size_t)b1 * T_SEQ * 32 + j;

  float m10 = 0.f, m20 = 0.f, mo0 = 0.f, s10 = 0.f, s20 = 0.f;
  float m11 = 0.f, m21 = 0.f, mo1 = 0.f, s11 = 0.f, s21 = 0.f;

  for (int ch = 0; ch < 48; ++ch) {
    float parts0[2], parts1[2];
    #pragma unroll
    for (int half = 0; half < 2; ++half) {
      float x0[12], x1[12];
      #pragma unroll
      for (int u = 0; u < 12; ++u) {
        int t = ch * 24 + half * 12 + u;
        x0[u] = base0[(size_t)t * 32];
        x1[u] = base1[(size_t)t * 32];
      }
      float acc0 = 0.f, acc1 = 0.f;
      #pragma unroll
      for (int u = 0; u < 12; ++u) {
        m10 = m10 * 0.8f + x0[u];
        float sp1a = (m10 > 0.5f) ? 1.f : 0.f;  m10 -= sp1a * 0.5f;
        m20 = m20 * 0.9f + sp1a;
        float sp2a = (m20 > 0.5f) ? 1.f : 0.f;  m20 -= sp2a * 0.5f;
        mo0 = mo0 * 0.95f + sp2a;
        s10 += sp1a; s20 += sp2a; acc0 += mo0;

        m11 = m11 * 0.8f + x1[u];
        float sp1b = (m11 > 0.5f) ? 1.f : 0.f;  m11 -= sp1b * 0.5f;
        m21 = m21 * 0.9f + sp1b;
        float sp2b = (m21 > 0.5f) ? 1.f : 0.f;  m21 -= sp2b * 0.5f;
        mo1 = mo1 * 0.95f + sp2b;
        s11 += sp1b; s21 += sp2b; acc1 += mo1;
      }
      parts0[half] = acc0; parts1[half] = acc1;
    }
    flat[b0 * 3072 + ch * 64 + j]      = parts0[0] / 12.0f;
    flat[b0 * 3072 + ch * 64 + 32 + j] = parts0[1] / 12.0f;
    flat[b1 * 3072 + ch * 64 + j]      = parts1[0] / 12.0f;
    flat[b1 * 3072 + ch * 64 + 32 + j] = parts1[1] / 12.0f;
  }
  for (int off = 16; off > 0; off >>= 1) {
    s10 += __shfl_down(s10, off, 32);
    s20 += __shfl_down(s20, off, 32);
    s11 += __shfl_down(s11, off, 32);
    s21 += __shfl_down(s21, off, 32);
  }
  if (j == 0) {
    spkPart[b0 * 2] = s10; spkPart[b0 * 2 + 1] = s20;
    spkPart[b1 * 2] = s11; spkPart[b1 * 2 + 1] = s21;
  }
}

// ---------------------------------------------------------------------------
// Kernel C: y = gelu(flat @ W1 + b1); logits = y @ W2 + b2 ; firing rate.
// ---------------------------------------------------------------------------
__global__ void mlpKernel(const float* __restrict__ flat, const float* __restrict__ W1,
                          const float* __restrict__ b1, const float* __restrict__ W2,
                          const float* __restrict__ b2, const float* __restrict__ spkPart,
                          float* __restrict__ out) {
  if (blockIdx.x == 64) {
    if (threadIdx.x == 0) {
      float s1 = 0.f, s2 = 0.f;
      for (int i = 0; i < 64; ++i) { s1 += spkPart[2 * i]; s2 += spkPart[2 * i + 1]; }
      out[256] = (s1 + s2) * 0.5f / (64.0f * 1152.0f * 32.0f);
    }
    return;
  }
  const int b = blockIdx.x;
  const int tid = threadIdx.x;        // 256
  const int u = tid & 31, kc = tid >> 5;
  __shared__ float red[256];
  __shared__ float ys[32];
  float p = 0.f;
  const int kbeg = kc * 384, kend = kbeg + 384;
  #pragma unroll 4
  for (int k = kbeg; k < kend; ++k)
    p = fmaf(flat[b * 3072 + k], W1[k * 32 + u], p);
  red[tid] = p;
  __syncthreads();
  if (kc == 0) {
    float y = b1[u];
    #pragma unroll
    for (int q = 0; q < 8; ++q) y += red[q * 32 + u];
    float y3 = y * y * y;
    float th = tanhf(0.7978845608028654f * (y + 0.044715f * y3));
    ys[u] = 0.5f * y * (1.0f + th);
  }
  __syncthreads();
  if (tid < 4) {
    float accv = b2[tid];
    #pragma unroll
    for (int q = 0; q < 32; ++q) accv = fmaf(ys[q], W2[q * 4 + tid], accv);
    out[b * 4 + tid] = accv;
  }
}

// ---------------------------------------------------------------------------
extern "C" void kernel_launch(void* const* d_in, const int* in_sizes, int n_in,
                              void* d_out, int out_size, void* d_ws, size_t ws_size,
                              hipStream_t stream) {
  const float* L   = (const float*)d_in[0];
  const float* X   = (const float*)d_in[1];
  // d_in[2] = deterministic (unused)
  const float* Kw  = (const float*)d_in[3];
  const float* lnS = (const float*)d_in[4];
  const float* lnB = (const float*)d_in[5];
  const float* sw  = (const float*)d_in[6];
  const float* W1  = (const float*)d_in[7];
  const float* b1  = (const float*)d_in[8];
  const float* W2  = (const float*)d_in[9];
  const float* b2  = (const float*)d_in[10];

  float* ws   = (float*)d_ws;
  float* Mbuf = ws;                       // 64*4*64      = 16384
  float* snn  = Mbuf + 16384;             // 64*1152*32   = 2359296
  float* flat = snn + 2359296;            // 64*3072      = 196608
  float* spk  = flat + 196608;            // 128
  float* out  = (float*)d_out;

  mKernel<<<64, 256, 0, stream>>>(L, sw, Mbuf);
  convKernel<<<1152, 256, 0, stream>>>(X, Kw, lnS, lnB, Mbuf, snn);
  scanKernel<<<16, 64, 0, stream>>>(snn, flat, spk);
  mlpKernel<<<65, 256, 0, stream>>>(flat, W1, b1, W2, b2, spk, out);
}

// Round 7
// 180.671 us; speedup vs baseline: 2.0594x; 1.6319x over previous
//
#include <hip/hip_runtime.h>
#include <hip/hip_fp16.h>
#include <math.h>

#define T_SEQ 1152

typedef _Float16 f16x8 __attribute__((ext_vector_type(8)));
typedef float f32x4 __attribute__((ext_vector_type(4)));

// DPP quad butterfly (xor1, xor2) — sums over the 4 lanes of each quad.
template <int CTRL>
__device__ __forceinline__ float xadd(float v) {
  int i = __builtin_bit_cast(int, v);
  int p = __builtin_amdgcn_update_dpp(i, i, CTRL, 0xf, 0xf, false);
  return v + __builtin_bit_cast(float, p);
}
__device__ __forceinline__ float qsum(float v) {
  return xadd<0x4E>(xadd<0xB1>(v));   // xor1 then xor2
}

// ---------------------------------------------------------------------------
// Kernel 0: M[b,m,s] = sum_n spatial_w[n,s] * L_norm[b,n,m]  (transposed out)
// ---------------------------------------------------------------------------
__global__ void mKernel(const float* __restrict__ L, const float* __restrict__ sw,
                        float* __restrict__ Mbuf) {
  int b = blockIdx.x, tid = threadIdx.x;   // 256 threads
  int s = tid >> 6, m = tid & 63;
  float a = 0.f;
  #pragma unroll 4
  for (int n = 0; n < 64; ++n)
    a = fmaf(sw[n * 4 + s], L[(b * 64 + n) * 64 + m], a);
  Mbuf[b * 256 + m * 4 + s] = a;           // [b][m][s]
}

// ---------------------------------------------------------------------------
// Kernel A (fp16 MFMA + per-thread LN/proj):
//   conv(32x1, 8->8, SAME) + LayerNorm(8) + ReLU + projection -> snn[b,t,32]
// GEMM view: out[(t), f] = sum_{kh,i} X[t+kh-15, c, i] * K[kh, i, f], per c.
// mfma_f32_16x16x32_f16, single term (fp16 quantization; ~1e-3 snn err).
// Block 256 thr = 4 waves; 64 t per block (16/wave); 8 c-parts of 8.
// Per part: stage fp16 X rows -> B1 -> MFMA (8 c2, write hT) -> B2 ->
//           per-thread LN + proj (2 (t,c) points / thread, f local).
// Epilogue: DPP quad reduction over the 4 c-owners of each t, coalesced store.
// ---------------------------------------------------------------------------
__global__ __launch_bounds__(256, 4)
void convKernel(const float* __restrict__ X, const float* __restrict__ Kw,
                const float* __restrict__ lnS, const float* __restrict__ lnB,
                const float* __restrict__ Mbuf, float* __restrict__ snn) {
  __shared__ int4  XS[8 * 97];    // [c2][tl] fp16x8 rows (stride 97 -> bank shift)
  __shared__ float hT[4 * 1160];  // per-wave [c2][t(stride 9)][f], c2 stride 145

  const int bid  = blockIdx.x;         // 0..1151
  const int b    = bid / 18;
  const int tile = bid - b * 18;       // 0..17
  const int t0   = tile * 64;
  const int tid  = threadIdx.x;        // 0..255
  const int lane = tid & 63;
  const int wid  = tid >> 6;           // wave 0..3
  const int w16  = wid * 16;           // wave's t offset in tile
  const int f    = lane & 15;          // MFMA col (f<8 real)
  const int rg   = lane >> 4;          // k-group / row group
  const bool f8  = (f < 8);

  // ---- B-frags: K[kh][i][f] -> fp16, lane holds col f; k = rg*8 + j, kh=4q+rg
  f16x8 bf[8];
  #pragma unroll
  for (int q = 0; q < 8; ++q) {
    #pragma unroll
    for (int j = 0; j < 8; ++j) {
      float kv = f8 ? Kw[(4 * q + rg) * 64 + j * 8 + f] : 0.f;
      bf[q][j] = (_Float16)kv;
    }
  }

  // ---- hoisted staging slots: lane = c-fast -> coalesced 256B chunks
  const int sc2 = tid & 7;             // staging channel 0..7
  int  stl[3];
  long gb[3];
  bool tv[3];
  #pragma unroll
  for (int k = 0; k < 3; ++k) {
    stl[k] = (tid >> 3) + 32 * k;      // 0..94 (+)
    int tt = t0 - 15 + stl[k];
    tv[k] = (tt >= 0) && (tt < T_SEQ);
    gb[k] = (long)tt * 512 + sc2 * 8;
  }
  const float* xb = X + (size_t)(b * T_SEQ) * 512;

  float pacc[4][8];
  #pragma unroll
  for (int s = 0; s < 4; ++s)
    #pragma unroll
    for (int ff = 0; ff < 8; ++ff) pacc[s][ff] = 0.f;

  const int rowb = w16 + (lane & 15) + rg;   // A-frag base row (tl units)
  const int tl   = lane >> 2;                // proj: thread's local t 0..15
  const int c2a  = (lane & 3) * 2;           // proj: thread's channel pair
  const float* hw = hT + wid * 1160;

  #pragma unroll 1
  for (int part = 0; part < 8; ++part) {
    // ---- stage X rows -> fp16 XS   (write XS; prev MFMA reads done via B2)
    #pragma unroll
    for (int k = 0; k < 3; ++k) {
      if (tid + 256 * k < 760) {
        float4 a0 = make_float4(0.f, 0.f, 0.f, 0.f);
        float4 a1 = make_float4(0.f, 0.f, 0.f, 0.f);
        if (tv[k]) {
          const float* p = xb + gb[k] + part * 64;
          a0 = *(const float4*)p;
          a1 = *(const float4*)(p + 4);
        }
        unsigned u0 = __builtin_bit_cast(unsigned, __float22half2_rn(make_float2(a0.x, a0.y)));
        unsigned u1 = __builtin_bit_cast(unsigned, __float22half2_rn(make_float2(a0.z, a0.w)));
        unsigned u2 = __builtin_bit_cast(unsigned, __float22half2_rn(make_float2(a1.x, a1.y)));
        unsigned u3 = __builtin_bit_cast(unsigned, __float22half2_rn(make_float2(a1.z, a1.w)));
        int4 v;
        v.x = (int)u0; v.y = (int)u1; v.z = (int)u2; v.w = (int)u3;
        XS[sc2 * 97 + stl[k]] = v;
      }
    }
    __syncthreads();   // B1: XS ready

    // ---- MFMA: per c2, 8 k-slices; write acc -> hT (per-wave region)
    #pragma unroll 2
    for (int c2 = 0; c2 < 8; ++c2) {
      f32x4 acc = {0.f, 0.f, 0.f, 0.f};
      const int rb = c2 * 97 + rowb;
      #pragma unroll
      for (int q = 0; q < 8; ++q) {
        f16x8 af = __builtin_bit_cast(f16x8, XS[rb + 4 * q]);
        acc = __builtin_amdgcn_mfma_f32_16x16x32_f16(af, bf[q], acc, 0, 0, 0);
      }
      if (f8) {
        int ha = wid * 1160 + c2 * 145 + rg * 36 + f;
        hT[ha]      = acc[0];
        hT[ha + 9]  = acc[1];
        hT[ha + 18] = acc[2];
        hT[ha + 27] = acc[3];
      }
    }
    __syncthreads();   // B2: hT ready; also licenses next stage's XS overwrite

    // ---- per-thread LN + ReLU + proj for 2 points (t, c2a), (t, c2a+1)
    {
      float pa[8], pb[8];
      const int hb = c2a * 145 + tl * 9;
      #pragma unroll
      for (int ff = 0; ff < 8; ++ff) pa[ff] = hw[hb + ff];
      #pragma unroll
      for (int ff = 0; ff < 8; ++ff) pb[ff] = hw[hb + 145 + ff];

      const float4 Ma = *(const float4*)(Mbuf + b * 256 + (part * 8 + c2a) * 4);
      const float4 Mb = *(const float4*)(Mbuf + b * 256 + (part * 8 + c2a + 1) * 4);

      float ha[8], hbv[8];
      {
        float mu = 0.f, mv = 0.f;
        #pragma unroll
        for (int ff = 0; ff < 8; ++ff) { mu += pa[ff]; mv += pb[ff]; }
        mu *= 0.125f; mv *= 0.125f;
        float va = 0.f, vb = 0.f;
        #pragma unroll
        for (int ff = 0; ff < 8; ++ff) {
          float da = pa[ff] - mu, db = pb[ff] - mv;
          pa[ff] = da; pb[ff] = db;
          va = fmaf(da, da, va); vb = fmaf(db, db, vb);
        }
        float ra = 1.0f / sqrtf(va * 0.125f + 1e-6f);
        float rb2 = 1.0f / sqrtf(vb * 0.125f + 1e-6f);
        #pragma unroll
        for (int ff = 0; ff < 8; ++ff) {
          ha[ff]  = fmaxf(fmaf(pa[ff] * ra,  lnS[ff], lnB[ff]), 0.f);
          hbv[ff] = fmaxf(fmaf(pb[ff] * rb2, lnS[ff], lnB[ff]), 0.f);
        }
      }
      #pragma unroll
      for (int ff = 0; ff < 8; ++ff) {
        pacc[0][ff] = fmaf(ha[ff], Ma.x, fmaf(hbv[ff], Mb.x, pacc[0][ff]));
        pacc[1][ff] = fmaf(ha[ff], Ma.y, fmaf(hbv[ff], Mb.y, pacc[1][ff]));
        pacc[2][ff] = fmaf(ha[ff], Ma.z, fmaf(hbv[ff], Mb.z, pacc[2][ff]));
        pacc[3][ff] = fmaf(ha[ff], Ma.w, fmaf(hbv[ff], Mb.w, pacc[3][ff]));
      }
    }
  }

  // ---- reduce over the 4 quad lanes (c-owners of this t), coalesced store
  #pragma unroll
  for (int s = 0; s < 4; ++s)
    #pragma unroll
    for (int ff = 0; ff < 8; ++ff) pacc[s][ff] = qsum(pacc[s][ff]);

  {
    const int q = lane & 3;
    float* op = snn + ((size_t)b * T_SEQ + t0 + w16 + tl) * 32 + q * 8;
    float4 lo4, hi4;
    switch (q) {
      case 0:
        lo4 = make_float4(pacc[0][0], pacc[0][1], pacc[0][2], pacc[0][3]);
        hi4 = make_float4(pacc[0][4], pacc[0][5], pacc[0][6], pacc[0][7]); break;
      case 1:
        lo4 = make_float4(pacc[1][0], pacc[1][1], pacc[1][2], pacc[1][3]);
        hi4 = make_float4(pacc[1][4], pacc[1][5], pacc[1][6], pacc[1][7]); break;
      case 2:
        lo4 = make_float4(pacc[2][0], pacc[2][1], pacc[2][2], pacc[2][3]);
        hi4 = make_float4(pacc[2][4], pacc[2][5], pacc[2][6], pacc[2][7]); break;
      default:
        lo4 = make_float4(pacc[3][0], pacc[3][1], pacc[3][2], pacc[3][3]);
        hi4 = make_float4(pacc[3][4], pacc[3][5], pacc[3][6], pacc[3][7]); break;
    }
    *(float4*)op       = lo4;
    *(float4*)(op + 4) = hi4;
  }
}

// ---------------------------------------------------------------------------
// Kernel B: LIF scan. 16 blocks x 64 threads; each thread runs TWO (b,j)
// chains interleaved for ILP on the dependent-FMA chain.
// ---------------------------------------------------------------------------
__global__ void scanKernel(const float* __restrict__ snn, float* __restrict__ flat,
                           float* __restrict__ spkPart) {
  const int tid = threadIdx.x;        // 0..63
  const int j = tid & 31;
  const int g = tid >> 5;             // 0..1
  const int pr = blockIdx.x * 2 + g;  // pair 0..31
  const int b0 = pr * 2, b1 = b0 + 1;
  const float* base0 = snn + (size_t)b0 * T_SEQ * 32 + j;
  const float* base1 = snn + (size_t)b1 * T_SEQ * 32 + j;

  float m10 = 0.f, m20 = 0.f, mo0 = 0.f, s10 = 0.f, s20 = 0.f;
  float m11 = 0.f, m21 = 0.f, mo1 = 0.f, s11 = 0.f, s21 = 0.f;

  for (int ch = 0; ch < 48; ++ch) {
    float parts0[2], parts1[2];
    #pragma unroll
    for (int half = 0; half < 2; ++half) {
      float x0[12], x1[12];
      #pragma unroll
      for (int u = 0; u < 12; ++u) {
        int t = ch * 24 + half * 12 + u;
        x0[u] = base0[(size_t)t * 32];
        x1[u] = base1[(size_t)t * 32];
      }
      float acc0 = 0.f, acc1 = 0.f;
      #pragma unroll
      for (int u = 0; u < 12; ++u) {
        m10 = m10 * 0.8f + x0[u];
        float sp1a = (m10 > 0.5f) ? 1.f : 0.f;  m10 -= sp1a * 0.5f;
        m20 = m20 * 0.9f + sp1a;
        float sp2a = (m20 > 0.5f) ? 1.f : 0.f;  m20 -= sp2a * 0.5f;
        mo0 = mo0 * 0.95f + sp2a;
        s10 += sp1a; s20 += sp2a; acc0 += mo0;

        m11 = m11 * 0.8f + x1[u];
        float sp1b = (m11 > 0.5f) ? 1.f : 0.f;  m11 -= sp1b * 0.5f;
        m21 = m21 * 0.9f + sp1b;
        float sp2b = (m21 > 0.5f) ? 1.f : 0.f;  m21 -= sp2b * 0.5f;
        mo1 = mo1 * 0.95f + sp2b;
        s11 += sp1b; s21 += sp2b; acc1 += mo1;
      }
      parts0[half] = acc0; parts1[half] = acc1;
    }
    flat[b0 * 3072 + ch * 64 + j]      = parts0[0] / 12.0f;
    flat[b0 * 3072 + ch * 64 + 32 + j] = parts0[1] / 12.0f;
    flat[b1 * 3072 + ch * 64 + j]      = parts1[0] / 12.0f;
    flat[b1 * 3072 + ch * 64 + 32 + j] = parts1[1] / 12.0f;
  }
  for (int off = 16; off > 0; off >>= 1) {
    s10 += __shfl_down(s10, off, 32);
    s20 += __shfl_down(s20, off, 32);
    s11 += __shfl_down(s11, off, 32);
    s21 += __shfl_down(s21, off, 32);
  }
  if (j == 0) {
    spkPart[b0 * 2] = s10; spkPart[b0 * 2 + 1] = s20;
    spkPart[b1 * 2] = s11; spkPart[b1 * 2 + 1] = s21;
  }
}

// ---------------------------------------------------------------------------
// Kernel C: y = gelu(flat @ W1 + b1); logits = y @ W2 + b2 ; firing rate.
// ---------------------------------------------------------------------------
__global__ void mlpKernel(const float* __restrict__ flat, const float* __restrict__ W1,
                          const float* __restrict__ b1, const float* __restrict__ W2,
                          const float* __restrict__ b2, const float* __restrict__ spkPart,
                          float* __restrict__ out) {
  if (blockIdx.x == 64) {
    if (threadIdx.x == 0) {
      float s1 = 0.f, s2 = 0.f;
      for (int i = 0; i < 64; ++i) { s1 += spkPart[2 * i]; s2 += spkPart[2 * i + 1]; }
      out[256] = (s1 + s2) * 0.5f / (64.0f * 1152.0f * 32.0f);
    }
    return;
  }
  const int b = blockIdx.x;
  const int tid = threadIdx.x;        // 256
  const int u = tid & 31, kc = tid >> 5;
  __shared__ float red[256];
  __shared__ float ys[32];
  float p = 0.f;
  const int kbeg = kc * 384, kend = kbeg + 384;
  #pragma unroll 4
  for (int k = kbeg; k < kend; ++k)
    p = fmaf(flat[b * 3072 + k], W1[k * 32 + u], p);
  red[tid] = p;
  __syncthreads();
  if (kc == 0) {
    float y = b1[u];
    #pragma unroll
    for (int q = 0; q < 8; ++q) y += red[q * 32 + u];
    float y3 = y * y * y;
    float th = tanhf(0.7978845608028654f * (y + 0.044715f * y3));
    ys[u] = 0.5f * y * (1.0f + th);
  }
  __syncthreads();
  if (tid < 4) {
    float accv = b2[tid];
    #pragma unroll
    for (int q = 0; q < 32; ++q) accv = fmaf(ys[q], W2[q * 4 + tid], accv);
    out[b * 4 + tid] = accv;
  }
}

// ---------------------------------------------------------------------------
extern "C" void kernel_launch(void* const* d_in, const int* in_sizes, int n_in,
                              void* d_out, int out_size, void* d_ws, size_t ws_size,
                              hipStream_t stream) {
  const float* L   = (const float*)d_in[0];
  const float* X   = (const float*)d_in[1];
  // d_in[2] = deterministic (unused)
  const float* Kw  = (const float*)d_in[3];
  const float* lnS = (const float*)d_in[4];
  const float* lnB = (const float*)d_in[5];
  const float* sw  = (const float*)d_in[6];
  const float* W1  = (const float*)d_in[7];
  const float* b1  = (const float*)d_in[8];
  const float* W2  = (const float*)d_in[9];
  const float* b2  = (const float*)d_in[10];

  float* ws   = (float*)d_ws;
  float* Mbuf = ws;                       // 64*4*64      = 16384
  float* snn  = Mbuf + 16384;             // 64*1152*32   = 2359296
  float* flat = snn + 2359296;            // 64*3072      = 196608
  float* spk  = flat + 196608;            // 128
  float* out  = (float*)d_out;

  mKernel<<<64, 256, 0, stream>>>(L, sw, Mbuf);
  convKernel<<<1152, 256, 0, stream>>>(X, Kw, lnS, lnB, Mbuf, snn);
  scanKernel<<<16, 64, 0, stream>>>(snn, flat, spk);
  mlpKernel<<<65, 256, 0, stream>>>(flat, W1, b1, W2, b2, spk, out);
}